// Round 2
// baseline (100.257 us; speedup 1.0000x reference)
//
#include <hip/hip_runtime.h>

// Problem constants (match reference)
#define BB 8
#define NN 512
#define NUM_GT 64
#define CC 16
#define FH 16
#define FW 16

// Output layout (floats):
//   label_map: [B*N][C][FH][FW]  -> 4096*4096 = 16777216
//   offset:    [B*N][4][FH][FW]  -> 4096*1024 =  4194304
//   mask:      [B*N][C]          -> 4096*16   =    65536
#define LM_FLOATS (BB*NN*CC*FH*FW)        // 16777216
#define OFF_FLOATS (BB*NN*4*FH*FW)        // 4194304

typedef float fv4 __attribute__((ext_vector_type(4)));

__global__ __launch_bounds__(256) void rcnn_encode_kernel(
    const float* __restrict__ boxes,          // (B,N,4)
    const float* __restrict__ gt_boxes,       // (B,NUM_GT,5)
    const int*   __restrict__ match_pos_flag, // (B,N)
    const int*   __restrict__ match_gt_id,    // (B,N)
    float* __restrict__ out)
{
    const int bn  = blockIdx.x;          // 0..B*N-1
    const int b   = bn >> 9;             // bn / N  (N=512)
    const int tid = threadIdx.x;         // 0..255

    // ---- per-(b,n) scalars (computed redundantly; loads broadcast) ----
    const fv4 bx = ((const fv4*)boxes)[bn];

    const int gid  = match_gt_id[bn];
    const int gidc = min(max(gid, 0), NUM_GT-1);       // clamp like reference
    const float* g = gt_boxes + (size_t)(b*NUM_GT + gidc)*5;
    const float gx1 = g[0], gy1 = g[1], gx2 = g[2], gy2 = g[3], label = g[4];
    const int flag = match_pos_flag[bn];

    // zoom boxes by (1.1, 1.1)
    const float cx = (bx.x + bx.z) * 0.5f;
    const float cy = (bx.y + bx.w) * 0.5f;
    const float zw = (bx.z - bx.x) * 1.1f;
    const float zh = (bx.w - bx.y) * 1.1f;
    const float ax1 = cx - zw * 0.5f;
    const float ay1 = cy - zh * 0.5f;
    const float ax2 = cx + zw * 0.5f;
    const float ay2 = cy + zh * 0.5f;

    const float rx1 = gx1 - ax1;
    const float ry1 = gy1 - ay1;
    const float rx2 = gx2 - ax1;
    const float ry2 = gy2 - ay1;
    const float rw  = rx2 - rx1;
    const float rh  = ry2 - ry1;
    const float rcx = (rx1 + rx2) * 0.5f;
    const float rcy = (ry1 + ry2) * 0.5f;
    const float sw  = (ax2 - ax1) * 0.0625f;   // /FW (exact pow2)
    const float sh  = (ay2 - ay1) * 0.0625f;

    // fast reciprocals (threshold is 7.32 absolute — approx is free)
    const float rsw = __builtin_amdgcn_rcpf(sw);
    const float rsh = __builtin_amdgcn_rcpf(sh);

    const float w_sigma = rw * 0.5f * rsw;
    const float h_sigma = rh * 0.5f * rsh;
    const float w_sig_c = fmaxf(w_sigma, 0.5f);
    const float h_sig_c = fmaxf(h_sigma, 0.5f);
    const float rws = __builtin_amdgcn_rcpf(fmaxf(w_sigma, 1.5f));
    const float rhs = __builtin_amdgcn_rcpf(fmaxf(h_sigma, 1.5f));
    const float pos_w = rcx * rsw;
    const float pos_h = rcy * rsh;
    const bool  small = (sw < 0.01f) || (sh < 0.01f);

    // offset plane values (per-axis)
    const float ox1v = small ? 0.0f : rx1 * rsw;
    const float oy1v = small ? 0.0f : ry1 * rsh;
    const float ox2v = small ? 0.0f : rx2 * rsw;
    const float oy2v = small ? 0.0f : ry2 * rsh;

    const float c_match = fabsf(label) - 1.0f;   // float compare like reference

    // ---- label_map: 4096 floats per bn = 1024 fv4; 4 per thread ----
    // heat computed inline only on the matching channel (wave-uniform branch)
    {
        fv4* lm = (fv4*)out + (size_t)bn * 1024;
        #pragma unroll
        for (int k = 0; k < 4; ++k) {
            const int f = k*256 + tid;           // fv4 idx in [0,1024)
            const int c = f >> 6;                // channel (wave-uniform)
            fv4 v = (fv4)0.0f;
            if ((float)c == c_match && !small) {
                const int pbase = (f & 63) << 2; // pixel base, 4 consecutive
                const float fh_ = (float)(pbase >> 4);   // same row for all 4
                const float htv = (pos_h - fh_ - 0.5f) * rhs;
                const float hterm = htv * htv;
                const bool hcond = fabsf(fh_ + 0.5f - pos_h) < h_sig_c;
                #pragma unroll
                for (int j = 0; j < 4; ++j) {
                    const float fw_ = (float)((pbase & 15) + j);
                    const float wtv = (pos_w - fw_ - 0.5f) * rws;
                    const bool cond = hcond &&
                        (fabsf(fw_ + 0.5f - pos_w) < w_sig_c);
                    const float e = __expf(-(wtv*wtv + hterm));
                    v[j] = cond ? e : 0.0f;
                }
            }
            __builtin_nontemporal_store(v, &lm[f]);
        }
    }

    // ---- offset: 1024 floats per bn = 256 fv4; 1 per thread ----
    {
        fv4* of = (fv4*)(out + (size_t)LM_FLOATS) + (size_t)bn * 256;
        const int comp  = tid >> 6;              // 0..3 (wave-uniform)
        const int pbase = (tid & 63) << 2;       // 4 consecutive pixels
        fv4 v;
        #pragma unroll
        for (int j = 0; j < 4; ++j) {
            const int p = pbase + j;
            const float fw_ = (float)(p & 15);
            const float fh_ = (float)(p >> 4);
            float val;
            if      (comp == 0) val = ox1v - (fw_ + 0.5f);
            else if (comp == 1) val = oy1v - (fh_ + 0.5f);
            else if (comp == 2) val = ox2v - (fw_ + 0.5f);
            else                val = oy2v - (fh_ + 0.5f);
            v[j] = small ? 0.0f : val;
        }
        __builtin_nontemporal_store(v, &of[tid]);
    }

    // ---- mask: 16 floats per bn ----
    if (tid < CC) {
        const bool pos_match = flag > 0;
        const float nnl = (flag != 0) ? label : 0.0f;    // non_neg_label
        const bool mask_one = pos_match && (nnl > 0.0f); // CLS_ON_HARD=False
        const bool m = ((float)tid == c_match) && mask_one;
        out[(size_t)LM_FLOATS + (size_t)OFF_FLOATS + (size_t)bn*CC + tid] = m ? 1.0f : 0.0f;
    }
}

extern "C" void kernel_launch(void* const* d_in, const int* in_sizes, int n_in,
                              void* d_out, int out_size, void* d_ws, size_t ws_size,
                              hipStream_t stream) {
    const float* boxes          = (const float*)d_in[0];
    const float* gt_boxes       = (const float*)d_in[1];
    const int*   match_pos_flag = (const int*)d_in[2];
    const int*   match_gt_id    = (const int*)d_in[3];
    float* out = (float*)d_out;

    rcnn_encode_kernel<<<BB*NN, 256, 0, stream>>>(
        boxes, gt_boxes, match_pos_flag, match_gt_id, out);
}